// Round 1
// baseline (421.166 us; speedup 1.0000x reference)
//
#include <hip/hip_runtime.h>

#define BS 4
#define NF 512
#define HW 4096
#define C8 64
#define TI 32                       // i-rows per fused block

typedef unsigned short bfu;                                    // raw bf16 bits
typedef __attribute__((ext_vector_type(8))) short bf16x8;      // MFMA A/B frag (4 VGPRs)
typedef __attribute__((ext_vector_type(4))) float f32x4;       // MFMA C/D frag

static __device__ __forceinline__ bfu f2bu(float v) {
    union { unsigned int u; float f; } c; c.f = v;
    unsigned int u = c.u;
    u = u + 0x7FFFu + ((u >> 16) & 1u);   // round-to-nearest-even
    return (bfu)(u >> 16);
}

// async global->LDS, 16 B per lane (global_load_lds_dwordx4)
static __device__ __forceinline__ void gload16(const void* g, void* l) {
    __builtin_amdgcn_global_load_lds(
        (const __attribute__((address_space(1))) unsigned int*)g,
        (__attribute__((address_space(3))) unsigned int*)l,
        16, 0, 0);
}

// ---------------- k0: x fp32 [b][c][n] -> xt bf16 [b][n][c] ----------------
__global__ __launch_bounds__(256) void k0_xt(const float* __restrict__ x, bfu* __restrict__ xt)
{
    __shared__ float T[64][68];                 // pad 68: float4 aligned, ~2-way banks
    const int t  = threadIdx.x;
    const int n0 = blockIdx.x * 64;
    const int c0 = blockIdx.y * 64;
    const int b  = blockIdx.z;

    #pragma unroll
    for (int u = 0; u < 4; u++) {
        int f4 = u * 256 + t;
        int cc = f4 >> 4;
        int n4 = (f4 & 15) << 2;
        float4 v = *(const float4*)(x + ((size_t)(b * NF + c0 + cc)) * HW + n0 + n4);
        *(float4*)&T[cc][n4] = v;
    }
    __syncthreads();
    #pragma unroll
    for (int u = 0; u < 2; u++) {
        int e8 = u * 256 + t;
        int nn = e8 >> 3;
        int c8 = (e8 & 7) << 3;
        union { int4 i4; bfu h[8]; } pk;
        #pragma unroll
        for (int q = 0; q < 8; q++) pk.h[q] = f2bu(T[c8 + q][nn]);
        *(int4*)(xt + ((size_t)(b * HW + n0 + nn)) * NF + c0 + c8) = pk.i4;
    }
}

// ---------------- k0b: Wq|Wk|Wv -> Wb bf16 [640][512]; biases -> bcat[640] ----------------
__global__ __launch_bounds__(256) void k0_w(const float* __restrict__ Wq, const float* __restrict__ bq,
                                            const float* __restrict__ Wk, const float* __restrict__ bk,
                                            const float* __restrict__ Wv, const float* __restrict__ bv,
                                            bfu* __restrict__ Wb, float* __restrict__ bcat)
{
    const int o = blockIdx.x;                   // 0..639
    const int t = threadIdx.x;
    const float* src; float bias;
    if (o < 64)       { src = Wq + (size_t)o * NF;          bias = bq[o]; }
    else if (o < 128) { src = Wk + (size_t)(o - 64) * NF;   bias = bk[o - 64]; }
    else              { src = Wv + (size_t)(o - 128) * NF;  bias = bv[o - 128]; }
    float2 v = *(const float2*)(src + t * 2);
    Wb[(size_t)o * NF + t * 2 + 0] = f2bu(v.x);
    Wb[(size_t)o * NF + t * 2 + 1] = f2bu(v.y);
    if (t == 0) bcat[o] = bias;
}

// ---------------- k1: Out[o][n] = Wb(640x512) . xt[b]^T, scatter into Qb/Kb/Vb ----------------
// 128x128 tile, BK=64, global_load_lds staging (m97 skeleton).
__global__ __launch_bounds__(256) void k1_proj(const bfu* __restrict__ Wb, const float* __restrict__ bcat,
                                               const bfu* __restrict__ xt,
                                               bfu* __restrict__ Qb, bfu* __restrict__ Kb, bfu* __restrict__ Vb)
{
    __shared__ bfu As[128 * 64];    // Wb tile: rows o (128), cols c (64)
    __shared__ bfu Bs[128 * 64];    // xt tile: rows n (128), cols c (64)
    const int t  = threadIdx.x;
    const int o0 = blockIdx.x * 128;
    const int n0 = blockIdx.y * 128;
    const int b  = blockIdx.z;
    const int lane = t & 63, wv = t >> 6;
    const int wm = wv & 1, wn = wv >> 1;
    const int l15 = lane & 15, quad = lane >> 4;

    const int srow = t >> 3;
    const int scol = (t & 7) * 8;

    const bfu* gA = Wb + ((size_t)(o0 + srow)) * NF + scol;
    const bfu* gB = xt + ((size_t)(b * HW + n0 + srow)) * NF + scol;
    bfu* lA = As + t * 8;
    bfu* lB = Bs + t * 8;

    f32x4 acc[4][4];
    #pragma unroll
    for (int m = 0; m < 4; m++)
        #pragma unroll
        for (int n = 0; n < 4; n++) acc[m][n] = (f32x4){0.f, 0.f, 0.f, 0.f};

    for (int c0 = 0; c0 < NF; c0 += 64) {
        __syncthreads();
        #pragma unroll
        for (int p = 0; p < 4; p++) {
            gload16(gA + (size_t)(p * 32) * NF + c0, lA + p * 2048);
            gload16(gB + (size_t)(p * 32) * NF + c0, lB + p * 2048);
        }
        __syncthreads();

        #pragma unroll
        for (int kk = 0; kk < 64; kk += 32) {
            bf16x8 Af[4], Bf[4];
            #pragma unroll
            for (int m = 0; m < 4; m++)
                Af[m] = *(const bf16x8*)(As + (wm * 64 + m * 16 + l15) * 64 + kk + quad * 8);
            #pragma unroll
            for (int n = 0; n < 4; n++)
                Bf[n] = *(const bf16x8*)(Bs + (wn * 64 + n * 16 + l15) * 64 + kk + quad * 8);
            #pragma unroll
            for (int m = 0; m < 4; m++)
                #pragma unroll
                for (int n = 0; n < 4; n++)
                    acc[m][n] = __builtin_amdgcn_mfma_f32_16x16x32_bf16(Af[m], Bf[n], acc[m][n], 0, 0, 0);
        }
    }

    #pragma unroll
    for (int mt = 0; mt < 4; mt++)
        #pragma unroll
        for (int nt = 0; nt < 4; nt++)
            #pragma unroll
            for (int r = 0; r < 4; r++) {
                int go = o0 + wm * 64 + mt * 16 + quad * 4 + r;      // out-channel 0..639
                int n  = n0 + wn * 64 + nt * 16 + l15;               // spatial index
                float val = acc[mt][nt][r] + bcat[go];
                if (go < 64)
                    Qb[((size_t)(b * HW + n)) * C8 + go] = f2bu(val);            // Q: [n][c]
                else if (go < 128)
                    Kb[((size_t)(b * HW + n)) * C8 + (go - 64)] = f2bu(val);     // K: [n][c]
                else
                    Vb[((size_t)(b * NF + (go - 128))) * HW + n] = f2bu(val);    // V: [c][n]
            }
}

// ---------------- k23: fused scores + softmax-numerator + PV + residual ----------------
// R1 change vs previous version:
//   * V is NOT staged through LDS anymore. Each V element was consumed by
//     exactly one wave (c-slab selects wave, quad selects j-slot), so the
//     64 KB Vs staging was pure overhead AND a 16-way bank conflict on every
//     PV ds_read_b128 (row stride 128 B = full bank wrap) — the measured
//     3.0e7 SQ_LDS_BANK_CONFLICT (~30% of cycles). V fragments now load
//     global->VGPR at the top of the chunk loop; L2 latency hides under the
//     S-step + barrier (T14 issue-early pattern).
//   * Ps is double-buffered -> ONE barrier per 64-j chunk instead of two
//     (no vmcnt staging drain at the barrier anymore either).
//   * XCD-aware block swizzle: batch b pinned to XCDs {2b, 2b+1} so each
//     XCD's V working set (4 MB) fits its private L2; the ~2 GB of V
//     re-reads become L2 hits instead of L3 traffic.
__global__ __launch_bounds__(512, 4) void k23_fused(const bfu* __restrict__ Kb, const bfu* __restrict__ Qb,
                                                    const bfu* __restrict__ Vb,
                                                    const float* __restrict__ x, const float* __restrict__ alpha,
                                                    float* __restrict__ out)
{
    __shared__ bfu   Ps[2][TI * 72];    // double-buffered P-tile, pad 72 for bank stagger
    __shared__ float LSum[8][16];
    __shared__ float Scale[TI];

    const int t = threadIdx.x;
    const int lane = t & 63, w = t >> 6;
    const int l15 = lane & 15, quad = lane >> 4;
    const int iq = w >> 2, jq = w & 3;  // S-subtile role
    const int cw = w * 64;              // PV slab: channels cw..cw+63

    // XCD swizzle: dispatch d -> XCD d&7 (round-robin heuristic). Map so that
    // XCDs 2b,2b+1 own batch b: each XCD re-reads exactly one batch's V (4 MB = L2).
    const int d    = blockIdx.x;        // 0..511
    const int xcd  = d & 7;
    const int slot = d >> 3;            // 0..63
    const int b    = xcd >> 1;
    const int i0   = ((xcd & 1) * 64 + slot) * TI;

    // persistent K fragments (B-side of S-MFMA): n = i = i0 + iq*16 + l15
    const bfu* kp = Kb + ((size_t)(b * HW + i0 + iq * 16 + l15)) * C8 + quad * 8;
    const bf16x8 Kf0 = *(const bf16x8*)kp;
    const bf16x8 Kf1 = *(const bf16x8*)(kp + 32);

    // Q stream base (A-side of S-MFMA): m = j = jb + jq*16 + l15
    const bfu* qbase = Qb + ((size_t)(b * HW + jq * 16 + l15)) * C8 + quad * 8;

    // V fragment base (A-side of PV-MFMA): row c = cw + mt*16 + l15, cols jb + quad*8 (+32)
    const bfu* vbase = Vb + ((size_t)(b * NF + cw + l15)) * HW + quad * 8;

    f32x4 acc[4][2];
    #pragma unroll
    for (int mt = 0; mt < 4; mt++)
        #pragma unroll
        for (int nt = 0; nt < 2; nt++) acc[mt][nt] = (f32x4){0.f, 0.f, 0.f, 0.f};
    float rsum = 0.f;

    for (int q = 0; q < HW / 64; q++) {
        const int jb = q * 64;
        bfu* Pq = Ps[q & 1];

        // (a) V fragments for this chunk: issue early so L2 latency hides
        //     under the S-step and the barrier. Zero reuse -> no LDS.
        bf16x8 Vf0[4], Vf1[4];
        #pragma unroll
        for (int mt = 0; mt < 4; mt++) {
            const bfu* vp = vbase + (size_t)(mt * 16) * HW + jb;
            Vf0[mt] = *(const bf16x8*)vp;
            Vf1[mt] = *(const bf16x8*)(vp + 32);
        }

        // (b) S-subtile: D[j][i] = Q[j][c] . K[i][c]
        const bfu* qp = qbase + (size_t)jb * C8;
        bf16x8 A0 = *(const bf16x8*)qp;
        bf16x8 A1 = *(const bf16x8*)(qp + 32);
        f32x4 s = (f32x4){0.f, 0.f, 0.f, 0.f};
        s = __builtin_amdgcn_mfma_f32_16x16x32_bf16(A0, Kf0, s, 0, 0, 0);
        s = __builtin_amdgcn_mfma_f32_16x16x32_bf16(A1, Kf1, s, 0, 0, 0);
        float e0 = __expf(s[0]);
        float e1 = __expf(s[1]);
        float e2 = __expf(s[2]);
        float e3 = __expf(s[3]);
        rsum += (e0 + e1) + (e2 + e3);
        uint2 pk;
        pk.x = (unsigned int)f2bu(e0) | ((unsigned int)f2bu(e1) << 16);
        pk.y = (unsigned int)f2bu(e2) | ((unsigned int)f2bu(e3) << 16);
        // lane's 4 values: rows j-local = jq*16 + quad*4 + r at col i-local = iq*16 + l15
        *(uint2*)(Pq + (iq * 16 + l15) * 72 + jq * 16 + quad * 4) = pk;

        __syncthreads();    // P-tile visible (double-buffered: prev chunk's reads already consumed)

        // (c) PV: D[c][i] += V[c][j] . P[i][j]
        bf16x8 Pf[2][2];
        #pragma unroll
        for (int nt = 0; nt < 2; nt++)
            #pragma unroll
            for (int kk = 0; kk < 2; kk++)
                Pf[nt][kk] = *(const bf16x8*)(Pq + (nt * 16 + l15) * 72 + kk * 32 + quad * 8);
        #pragma unroll
        for (int mt = 0; mt < 4; mt++) {
            #pragma unroll
            for (int nt = 0; nt < 2; nt++) {
                acc[mt][nt] = __builtin_amdgcn_mfma_f32_16x16x32_bf16(Vf0[mt], Pf[nt][0], acc[mt][nt], 0, 0, 0);
                acc[mt][nt] = __builtin_amdgcn_mfma_f32_16x16x32_bf16(Vf1[mt], Pf[nt][1], acc[mt][nt], 0, 0, 0);
            }
        }
    }

    // row-sum reduction: lane's rsum covers i = i0 + iq*16 + l15, j in its (jq,quad,r) set
    float sred = rsum;
    sred += __shfl_xor(sred, 16, 64);
    sred += __shfl_xor(sred, 32, 64);
    if (quad == 0) LSum[w][l15] = sred;
    __syncthreads();
    if (t < TI) {
        int iqq = t >> 4, il = t & 15;
        float L = (LSum[iqq * 4 + 0][il] + LSum[iqq * 4 + 1][il])
                + (LSum[iqq * 4 + 2][il] + LSum[iqq * 4 + 3][il]);
        Scale[t] = alpha[0] / L;
    }
    __syncthreads();

    #pragma unroll
    for (int nt = 0; nt < 2; nt++) {
        float sc = Scale[nt * 16 + l15];
        int i = i0 + nt * 16 + l15;
        #pragma unroll
        for (int mt = 0; mt < 4; mt++)
            #pragma unroll
            for (int r = 0; r < 4; r++) {
                int c = cw + mt * 16 + quad * 4 + r;
                size_t idx = ((size_t)(b * NF + c)) * HW + i;
                out[idx] = x[idx] + sc * acc[mt][nt][r];
            }
    }
}

extern "C" void kernel_launch(void* const* d_in, const int* in_sizes, int n_in,
                              void* d_out, int out_size, void* d_ws, size_t ws_size,
                              hipStream_t stream)
{
    const float* x     = (const float*)d_in[0];
    const float* Wq    = (const float*)d_in[1];
    const float* bq    = (const float*)d_in[2];
    const float* Wk    = (const float*)d_in[3];
    const float* bk    = (const float*)d_in[4];
    const float* Wv    = (const float*)d_in[5];
    const float* bv    = (const float*)d_in[6];
    const float* alpha = (const float*)d_in[7];
    float* out = (float*)d_out;

    char* ws = (char*)d_ws;
    bfu*   xt   = (bfu*)(ws);                                  // [0,16) MB : [b][n][c] bf16
    bfu*   Wb   = (bfu*)(ws + (16u << 20));                    // [16,~16.6) MB: [640][512] bf16
    float* bcat = (float*)(ws + (17u << 20));                  // 2.5 KB at 17 MB
    bfu*   Qb   = (bfu*)(ws + (18u << 20));                    // [18,20) MB : [b][n][64]
    bfu*   Kb   = (bfu*)(ws + (20u << 20));                    // [20,22) MB : [b][n][64]
    bfu*   Vb   = (bfu*)(ws + (22u << 20));                    // [22,38) MB : [b][c][n]  (16 MB)

    k0_xt<<<dim3(HW / 64, NF / 64, BS), 256, 0, stream>>>(x, xt);
    k0_w<<<dim3(640), 256, 0, stream>>>(Wq, bq, Wk, bk, Wv, bv, Wb, bcat);
    k1_proj<<<dim3(5, HW / 128, BS), 256, 0, stream>>>(Wb, bcat, xt, Qb, Kb, Vb);
    k23_fused<<<dim3((HW / TI) * BS), 512, 0, stream>>>(Kb, Qb, Vb, x, alpha, out);
}

// Round 2
// 284.229 us; speedup vs baseline: 1.4818x; 1.4818x over previous
//
#include <hip/hip_runtime.h>

#define BS 4
#define NF 512
#define HW 4096
#define C8 64
#define TI 32                       // i-rows per fused block

typedef unsigned short bfu;                                    // raw bf16 bits
typedef __attribute__((ext_vector_type(8))) short bf16x8;      // MFMA A/B frag (4 VGPRs)
typedef __attribute__((ext_vector_type(4))) float f32x4;       // MFMA C/D frag

static __device__ __forceinline__ bfu f2bu(float v) {
    union { unsigned int u; float f; } c; c.f = v;
    unsigned int u = c.u;
    u = u + 0x7FFFu + ((u >> 16) & 1u);   // round-to-nearest-even
    return (bfu)(u >> 16);
}

// async global->LDS, 16 B per lane (global_load_lds_dwordx4)
static __device__ __forceinline__ void gload16(const void* g, void* l) {
    __builtin_amdgcn_global_load_lds(
        (const __attribute__((address_space(1))) unsigned int*)g,
        (__attribute__((address_space(3))) unsigned int*)l,
        16, 0, 0);
}

// ---------------- k0: x fp32 [b][c][n] -> xt bf16 [b][n][c] ----------------
__global__ __launch_bounds__(256) void k0_xt(const float* __restrict__ x, bfu* __restrict__ xt)
{
    __shared__ float T[64][68];                 // pad 68: float4 aligned, ~2-way banks
    const int t  = threadIdx.x;
    const int n0 = blockIdx.x * 64;
    const int c0 = blockIdx.y * 64;
    const int b  = blockIdx.z;

    #pragma unroll
    for (int u = 0; u < 4; u++) {
        int f4 = u * 256 + t;
        int cc = f4 >> 4;
        int n4 = (f4 & 15) << 2;
        float4 v = *(const float4*)(x + ((size_t)(b * NF + c0 + cc)) * HW + n0 + n4);
        *(float4*)&T[cc][n4] = v;
    }
    __syncthreads();
    #pragma unroll
    for (int u = 0; u < 2; u++) {
        int e8 = u * 256 + t;
        int nn = e8 >> 3;
        int c8 = (e8 & 7) << 3;
        union { int4 i4; bfu h[8]; } pk;
        #pragma unroll
        for (int q = 0; q < 8; q++) pk.h[q] = f2bu(T[c8 + q][nn]);
        *(int4*)(xt + ((size_t)(b * HW + n0 + nn)) * NF + c0 + c8) = pk.i4;
    }
}

// ---------------- k0b: Wq|Wk|Wv -> Wb bf16 [640][512]; biases -> bcat[640] ----------------
__global__ __launch_bounds__(256) void k0_w(const float* __restrict__ Wq, const float* __restrict__ bq,
                                            const float* __restrict__ Wk, const float* __restrict__ bk,
                                            const float* __restrict__ Wv, const float* __restrict__ bv,
                                            bfu* __restrict__ Wb, float* __restrict__ bcat)
{
    const int o = blockIdx.x;                   // 0..639
    const int t = threadIdx.x;
    const float* src; float bias;
    if (o < 64)       { src = Wq + (size_t)o * NF;          bias = bq[o]; }
    else if (o < 128) { src = Wk + (size_t)(o - 64) * NF;   bias = bk[o - 64]; }
    else              { src = Wv + (size_t)(o - 128) * NF;  bias = bv[o - 128]; }
    float2 v = *(const float2*)(src + t * 2);
    Wb[(size_t)o * NF + t * 2 + 0] = f2bu(v.x);
    Wb[(size_t)o * NF + t * 2 + 1] = f2bu(v.y);
    if (t == 0) bcat[o] = bias;
}

// ---------------- k1: Out[o][n] = Wb(640x512) . xt[b]^T, scatter into Qb/Kb/Vb ----------------
// 128x128 tile, BK=64, global_load_lds staging (m97 skeleton).
__global__ __launch_bounds__(256) void k1_proj(const bfu* __restrict__ Wb, const float* __restrict__ bcat,
                                               const bfu* __restrict__ xt,
                                               bfu* __restrict__ Qb, bfu* __restrict__ Kb, bfu* __restrict__ Vb)
{
    __shared__ bfu As[128 * 64];    // Wb tile: rows o (128), cols c (64)
    __shared__ bfu Bs[128 * 64];    // xt tile: rows n (128), cols c (64)
    const int t  = threadIdx.x;
    const int o0 = blockIdx.x * 128;
    const int n0 = blockIdx.y * 128;
    const int b  = blockIdx.z;
    const int lane = t & 63, wv = t >> 6;
    const int wm = wv & 1, wn = wv >> 1;
    const int l15 = lane & 15, quad = lane >> 4;

    const int srow = t >> 3;
    const int scol = (t & 7) * 8;

    const bfu* gA = Wb + ((size_t)(o0 + srow)) * NF + scol;
    const bfu* gB = xt + ((size_t)(b * HW + n0 + srow)) * NF + scol;
    bfu* lA = As + t * 8;
    bfu* lB = Bs + t * 8;

    f32x4 acc[4][4];
    #pragma unroll
    for (int m = 0; m < 4; m++)
        #pragma unroll
        for (int n = 0; n < 4; n++) acc[m][n] = (f32x4){0.f, 0.f, 0.f, 0.f};

    for (int c0 = 0; c0 < NF; c0 += 64) {
        __syncthreads();
        #pragma unroll
        for (int p = 0; p < 4; p++) {
            gload16(gA + (size_t)(p * 32) * NF + c0, lA + p * 2048);
            gload16(gB + (size_t)(p * 32) * NF + c0, lB + p * 2048);
        }
        __syncthreads();

        #pragma unroll
        for (int kk = 0; kk < 64; kk += 32) {
            bf16x8 Af[4], Bf[4];
            #pragma unroll
            for (int m = 0; m < 4; m++)
                Af[m] = *(const bf16x8*)(As + (wm * 64 + m * 16 + l15) * 64 + kk + quad * 8);
            #pragma unroll
            for (int n = 0; n < 4; n++)
                Bf[n] = *(const bf16x8*)(Bs + (wn * 64 + n * 16 + l15) * 64 + kk + quad * 8);
            #pragma unroll
            for (int m = 0; m < 4; m++)
                #pragma unroll
                for (int n = 0; n < 4; n++)
                    acc[m][n] = __builtin_amdgcn_mfma_f32_16x16x32_bf16(Af[m], Bf[n], acc[m][n], 0, 0, 0);
        }
    }

    #pragma unroll
    for (int mt = 0; mt < 4; mt++)
        #pragma unroll
        for (int nt = 0; nt < 4; nt++)
            #pragma unroll
            for (int r = 0; r < 4; r++) {
                int go = o0 + wm * 64 + mt * 16 + quad * 4 + r;      // out-channel 0..639
                int n  = n0 + wn * 64 + nt * 16 + l15;               // spatial index
                float val = acc[mt][nt][r] + bcat[go];
                if (go < 64)
                    Qb[((size_t)(b * HW + n)) * C8 + go] = f2bu(val);            // Q: [n][c]
                else if (go < 128)
                    Kb[((size_t)(b * HW + n)) * C8 + (go - 64)] = f2bu(val);     // K: [n][c]
                else
                    Vb[((size_t)(b * NF + (go - 128))) * HW + n] = f2bu(val);    // V: [c][n]
            }
}

// ---------------- k23: fused scores + softmax-numerator + PV + residual ----------------
// R2: back to the R0 DMA-staged V (reg-V direct loads were a 2x regression:
// exposed L2 latency, MfmaUtil 20->10). The R0 structure's measured cost was
// ~30% LDS bank-conflict cycles (3.0e7) from the PV read of Vs[512][64]
// (row stride 128 B = full bank wrap -> 16 lanes/quad on the same 4 banks).
// Fix per rule #21 / m173: gload16's LDS dest must stay LINEAR, so the
// swizzle is applied as (a) pre-swizzled GLOBAL source column during staging
// and (b) the matching XOR on the PV ds_read slot:
//     Vs[row][slot] holds V[row][slot ^ (row&7)]   (slot = 8-elem / 16 B unit)
// PV read then puts 8 lanes on each of the 8 bank-quads (b128 minimum) ->
// conflict-free. Keeps R1's XCD-swizzled flat grid (FETCH halved 91->51 MB).
__global__ __launch_bounds__(512, 4) void k23_fused(const bfu* __restrict__ Kb, const bfu* __restrict__ Qb,
                                                    const bfu* __restrict__ Vb,
                                                    const float* __restrict__ x, const float* __restrict__ alpha,
                                                    float* __restrict__ out)
{
    __shared__ bfu   Vs[512 * 64];      // 64 KB, linear DMA dest; rows slot-swizzled
    __shared__ bfu   Ps[TI * 72];       // 4.5 KB, pad 72 for bank stagger
    __shared__ float LSum[8][16];
    __shared__ float Scale[TI];

    const int t = threadIdx.x;
    const int lane = t & 63, w = t >> 6;
    const int l15 = lane & 15, quad = lane >> 4;
    const int iq = w >> 2, jq = w & 3;  // S-subtile role
    const int cw = w * 64;              // PV slab: channels cw..cw+63

    // XCD swizzle: dispatch d -> XCD d&7 (round-robin). XCDs {2b,2b+1} own
    // batch b so each XCD's V working set (4 MB) maps to its private L2.
    const int d    = blockIdx.x;        // 0..511
    const int xcd  = d & 7;
    const int slot = d >> 3;            // 0..63
    const int b    = xcd >> 1;
    const int i0   = ((xcd & 1) * 64 + slot) * TI;

    // persistent K fragments (B-side of S-MFMA): n = i = i0 + iq*16 + l15
    const bfu* kp = Kb + ((size_t)(b * HW + i0 + iq * 16 + l15)) * C8 + quad * 8;
    const bf16x8 Kf0 = *(const bf16x8*)kp;
    const bf16x8 Kf1 = *(const bf16x8*)(kp + 32);

    // V staging: thread t fills LDS rows (t>>3)+64p at slot (t&7); the global
    // column is pre-swizzled so linear LDS receives the swizzled layout.
    // (row+64p) & 7 == row & 7, so the XOR term is loop-invariant.
    const int srow = t >> 3, sslot = t & 7;
    const bfu* gV = Vb + ((size_t)(b * NF + srow)) * HW + ((sslot ^ (srow & 7)) * 8);
    bfu* lV = Vs + t * 8;

    // Q stream base (A-side of S-MFMA): m = j = jb + jq*16 + l15
    const bfu* qbase = Qb + ((size_t)(b * HW + jq * 16 + l15)) * C8 + quad * 8;

    // swizzled PV read slots: row = cw + mt*16 + l15 -> row&7 == l15&7
    const int r7  = l15 & 7;
    const int sl0 = (quad ^ r7) * 8;            // element offset of Vf0's 16 B slot
    const int sl1 = ((quad + 4) ^ r7) * 8;      // Vf1

    f32x4 acc[4][2];
    #pragma unroll
    for (int mt = 0; mt < 4; mt++)
        #pragma unroll
        for (int nt = 0; nt < 2; nt++) acc[mt][nt] = (f32x4){0.f, 0.f, 0.f, 0.f};
    float rsum = 0.f;

    for (int q = 0; q < HW / 64; q++) {
        const int jb = q * 64;
        // (a) stage V[0..511][jb..jb+63] (swizzled source)
        #pragma unroll
        for (int p = 0; p < 8; p++)
            gload16(gV + (size_t)(p * 64) * HW + jb, lV + p * 4096);

        // (b) S-subtile: D[j][i] = Q[j][c] . K[i][c]
        const bfu* qp = qbase + (size_t)jb * C8;
        bf16x8 A0 = *(const bf16x8*)qp;
        bf16x8 A1 = *(const bf16x8*)(qp + 32);
        f32x4 s = (f32x4){0.f, 0.f, 0.f, 0.f};
        s = __builtin_amdgcn_mfma_f32_16x16x32_bf16(A0, Kf0, s, 0, 0, 0);
        s = __builtin_amdgcn_mfma_f32_16x16x32_bf16(A1, Kf1, s, 0, 0, 0);
        float e0 = __expf(s[0]);
        float e1 = __expf(s[1]);
        float e2 = __expf(s[2]);
        float e3 = __expf(s[3]);
        rsum += (e0 + e1) + (e2 + e3);
        uint2 pk;
        pk.x = (unsigned int)f2bu(e0) | ((unsigned int)f2bu(e1) << 16);
        pk.y = (unsigned int)f2bu(e2) | ((unsigned int)f2bu(e3) << 16);
        // lane's 4 values: rows j-local = jq*16 + quad*4 + r at col i-local = iq*16 + l15
        *(uint2*)(Ps + (iq * 16 + l15) * 72 + jq * 16 + quad * 4) = pk;

        __syncthreads();    // Vs staged (vmcnt drained) + Ps visible

        // (c) PV: D[c][i] += V[c][j] . P[i][j]
        bf16x8 Pf[2][2];
        #pragma unroll
        for (int nt = 0; nt < 2; nt++)
            #pragma unroll
            for (int kk = 0; kk < 2; kk++)
                Pf[nt][kk] = *(const bf16x8*)(Ps + (nt * 16 + l15) * 72 + kk * 32 + quad * 8);
        #pragma unroll
        for (int mt = 0; mt < 4; mt++) {
            const bfu* vrow = Vs + (cw + mt * 16 + l15) * 64;
            bf16x8 V0 = *(const bf16x8*)(vrow + sl0);
            bf16x8 V1 = *(const bf16x8*)(vrow + sl1);
            #pragma unroll
            for (int nt = 0; nt < 2; nt++) {
                acc[mt][nt] = __builtin_amdgcn_mfma_f32_16x16x32_bf16(V0, Pf[nt][0], acc[mt][nt], 0, 0, 0);
                acc[mt][nt] = __builtin_amdgcn_mfma_f32_16x16x32_bf16(V1, Pf[nt][1], acc[mt][nt], 0, 0, 0);
            }
        }
        __syncthreads();    // PV reads done -> next chunk may overwrite Vs/Ps
    }

    // row-sum reduction: lane's rsum covers i = i0 + iq*16 + l15, j in its (jq,quad,r) set
    float sred = rsum;
    sred += __shfl_xor(sred, 16, 64);
    sred += __shfl_xor(sred, 32, 64);
    if (quad == 0) LSum[w][l15] = sred;
    __syncthreads();
    if (t < TI) {
        int iqq = t >> 4, il = t & 15;
        float L = (LSum[iqq * 4 + 0][il] + LSum[iqq * 4 + 1][il])
                + (LSum[iqq * 4 + 2][il] + LSum[iqq * 4 + 3][il]);
        Scale[t] = alpha[0] / L;
    }
    __syncthreads();

    #pragma unroll
    for (int nt = 0; nt < 2; nt++) {
        float sc = Scale[nt * 16 + l15];
        int i = i0 + nt * 16 + l15;
        #pragma unroll
        for (int mt = 0; mt < 4; mt++)
            #pragma unroll
            for (int r = 0; r < 4; r++) {
                int c = cw + mt * 16 + quad * 4 + r;
                size_t idx = ((size_t)(b * NF + c)) * HW + i;
                out[idx] = x[idx] + sc * acc[mt][nt][r];
            }
    }
}

extern "C" void kernel_launch(void* const* d_in, const int* in_sizes, int n_in,
                              void* d_out, int out_size, void* d_ws, size_t ws_size,
                              hipStream_t stream)
{
    const float* x     = (const float*)d_in[0];
    const float* Wq    = (const float*)d_in[1];
    const float* bq    = (const float*)d_in[2];
    const float* Wk    = (const float*)d_in[3];
    const float* bk    = (const float*)d_in[4];
    const float* Wv    = (const float*)d_in[5];
    const float* bv    = (const float*)d_in[6];
    const float* alpha = (const float*)d_in[7];
    float* out = (float*)d_out;

    char* ws = (char*)d_ws;
    bfu*   xt   = (bfu*)(ws);                                  // [0,16) MB : [b][n][c] bf16
    bfu*   Wb   = (bfu*)(ws + (16u << 20));                    // [16,~16.6) MB: [640][512] bf16
    float* bcat = (float*)(ws + (17u << 20));                  // 2.5 KB at 17 MB
    bfu*   Qb   = (bfu*)(ws + (18u << 20));                    // [18,20) MB : [b][n][64]
    bfu*   Kb   = (bfu*)(ws + (20u << 20));                    // [20,22) MB : [b][n][64]
    bfu*   Vb   = (bfu*)(ws + (22u << 20));                    // [22,38) MB : [b][c][n]  (16 MB)

    k0_xt<<<dim3(HW / 64, NF / 64, BS), 256, 0, stream>>>(x, xt);
    k0_w<<<dim3(640), 256, 0, stream>>>(Wq, bq, Wk, bk, Wv, bv, Wb, bcat);
    k1_proj<<<dim3(5, HW / 128, BS), 256, 0, stream>>>(Wb, bcat, xt, Qb, Kb, Vb);
    k23_fused<<<dim3((HW / TI) * BS), 512, 0, stream>>>(Kb, Qb, Vb, x, alpha, out);
}

// Round 3
// 264.859 us; speedup vs baseline: 1.5901x; 1.0731x over previous
//
#include <hip/hip_runtime.h>

#define BS 4
#define NF 512
#define HW 4096
#define C8 64
#define TI 64                       // i-rows per fused block (R3: was 32)

typedef unsigned short bfu;                                    // raw bf16 bits
typedef __attribute__((ext_vector_type(8))) short bf16x8;      // MFMA A/B frag (4 VGPRs)
typedef __attribute__((ext_vector_type(4))) float f32x4;       // MFMA C/D frag

static __device__ __forceinline__ bfu f2bu(float v) {
    union { unsigned int u; float f; } c; c.f = v;
    unsigned int u = c.u;
    u = u + 0x7FFFu + ((u >> 16) & 1u);   // round-to-nearest-even
    return (bfu)(u >> 16);
}

// async global->LDS, 16 B per lane (global_load_lds_dwordx4)
static __device__ __forceinline__ void gload16(const void* g, void* l) {
    __builtin_amdgcn_global_load_lds(
        (const __attribute__((address_space(1))) unsigned int*)g,
        (__attribute__((address_space(3))) unsigned int*)l,
        16, 0, 0);
}

// ---------------- k0: x fp32 [b][c][n] -> xt bf16 [b][n][c] ----------------
__global__ __launch_bounds__(256) void k0_xt(const float* __restrict__ x, bfu* __restrict__ xt)
{
    __shared__ float T[64][68];                 // pad 68: float4 aligned, ~2-way banks
    const int t  = threadIdx.x;
    const int n0 = blockIdx.x * 64;
    const int c0 = blockIdx.y * 64;
    const int b  = blockIdx.z;

    #pragma unroll
    for (int u = 0; u < 4; u++) {
        int f4 = u * 256 + t;
        int cc = f4 >> 4;
        int n4 = (f4 & 15) << 2;
        float4 v = *(const float4*)(x + ((size_t)(b * NF + c0 + cc)) * HW + n0 + n4);
        *(float4*)&T[cc][n4] = v;
    }
    __syncthreads();
    #pragma unroll
    for (int u = 0; u < 2; u++) {
        int e8 = u * 256 + t;
        int nn = e8 >> 3;
        int c8 = (e8 & 7) << 3;
        union { int4 i4; bfu h[8]; } pk;
        #pragma unroll
        for (int q = 0; q < 8; q++) pk.h[q] = f2bu(T[c8 + q][nn]);
        *(int4*)(xt + ((size_t)(b * HW + n0 + nn)) * NF + c0 + c8) = pk.i4;
    }
}

// ---------------- k0b: Wq|Wk|Wv -> Wb bf16 [640][512]; biases -> bcat[640] ----------------
__global__ __launch_bounds__(256) void k0_w(const float* __restrict__ Wq, const float* __restrict__ bq,
                                            const float* __restrict__ Wk, const float* __restrict__ bk,
                                            const float* __restrict__ Wv, const float* __restrict__ bv,
                                            bfu* __restrict__ Wb, float* __restrict__ bcat)
{
    const int o = blockIdx.x;                   // 0..639
    const int t = threadIdx.x;
    const float* src; float bias;
    if (o < 64)       { src = Wq + (size_t)o * NF;          bias = bq[o]; }
    else if (o < 128) { src = Wk + (size_t)(o - 64) * NF;   bias = bk[o - 64]; }
    else              { src = Wv + (size_t)(o - 128) * NF;  bias = bv[o - 128]; }
    float2 v = *(const float2*)(src + t * 2);
    Wb[(size_t)o * NF + t * 2 + 0] = f2bu(v.x);
    Wb[(size_t)o * NF + t * 2 + 1] = f2bu(v.y);
    if (t == 0) bcat[o] = bias;
}

// ---------------- k1: Out[o][n] = Wb(640x512) . xt[b]^T, scatter into Qb/Kb/Vb ----------------
// 128x128 tile, BK=64, global_load_lds staging (m97 skeleton).
__global__ __launch_bounds__(256) void k1_proj(const bfu* __restrict__ Wb, const float* __restrict__ bcat,
                                               const bfu* __restrict__ xt,
                                               bfu* __restrict__ Qb, bfu* __restrict__ Kb, bfu* __restrict__ Vb)
{
    __shared__ bfu As[128 * 64];    // Wb tile: rows o (128), cols c (64)
    __shared__ bfu Bs[128 * 64];    // xt tile: rows n (128), cols c (64)
    const int t  = threadIdx.x;
    const int o0 = blockIdx.x * 128;
    const int n0 = blockIdx.y * 128;
    const int b  = blockIdx.z;
    const int lane = t & 63, wv = t >> 6;
    const int wm = wv & 1, wn = wv >> 1;
    const int l15 = lane & 15, quad = lane >> 4;

    const int srow = t >> 3;
    const int scol = (t & 7) * 8;

    const bfu* gA = Wb + ((size_t)(o0 + srow)) * NF + scol;
    const bfu* gB = xt + ((size_t)(b * HW + n0 + srow)) * NF + scol;
    bfu* lA = As + t * 8;
    bfu* lB = Bs + t * 8;

    f32x4 acc[4][4];
    #pragma unroll
    for (int m = 0; m < 4; m++)
        #pragma unroll
        for (int n = 0; n < 4; n++) acc[m][n] = (f32x4){0.f, 0.f, 0.f, 0.f};

    for (int c0 = 0; c0 < NF; c0 += 64) {
        __syncthreads();
        #pragma unroll
        for (int p = 0; p < 4; p++) {
            gload16(gA + (size_t)(p * 32) * NF + c0, lA + p * 2048);
            gload16(gB + (size_t)(p * 32) * NF + c0, lB + p * 2048);
        }
        __syncthreads();

        #pragma unroll
        for (int kk = 0; kk < 64; kk += 32) {
            bf16x8 Af[4], Bf[4];
            #pragma unroll
            for (int m = 0; m < 4; m++)
                Af[m] = *(const bf16x8*)(As + (wm * 64 + m * 16 + l15) * 64 + kk + quad * 8);
            #pragma unroll
            for (int n = 0; n < 4; n++)
                Bf[n] = *(const bf16x8*)(Bs + (wn * 64 + n * 16 + l15) * 64 + kk + quad * 8);
            #pragma unroll
            for (int m = 0; m < 4; m++)
                #pragma unroll
                for (int n = 0; n < 4; n++)
                    acc[m][n] = __builtin_amdgcn_mfma_f32_16x16x32_bf16(Af[m], Bf[n], acc[m][n], 0, 0, 0);
        }
    }

    #pragma unroll
    for (int mt = 0; mt < 4; mt++)
        #pragma unroll
        for (int nt = 0; nt < 4; nt++)
            #pragma unroll
            for (int r = 0; r < 4; r++) {
                int go = o0 + wm * 64 + mt * 16 + quad * 4 + r;      // out-channel 0..639
                int n  = n0 + wn * 64 + nt * 16 + l15;               // spatial index
                float val = acc[mt][nt][r] + bcat[go];
                if (go < 64)
                    Qb[((size_t)(b * HW + n)) * C8 + go] = f2bu(val);            // Q: [n][c]
                else if (go < 128)
                    Kb[((size_t)(b * HW + n)) * C8 + (go - 64)] = f2bu(val);     // K: [n][c]
                else
                    Vb[((size_t)(b * NF + (go - 128))) * HW + n] = f2bu(val);    // V: [c][n]
            }
}

// ---------------- k23: fused scores + softmax-numerator + PV + residual ----------------
// R3: pipeline the chunk loop (T3/T4) + TI=64.
//   * R2 post-mortem: 6380 cy/chunk vs ~160 cy MFMA + ~1150 cy L2 staging ->
//     the 2-barrier drain structure was ~75% stall (m233 regime). Fix = counted
//     vmcnt: stage chunk q+1 + prefetch Q(q+1) at iter top, s_waitcnt vmcnt(10)
//     (retires PREVIOUS iter's 8 stage + 2 Q loads; this iter's 10 stay in
//     flight across both raw s_barriers), PV on buffer pc while pn fills.
//   * TI=64: V L2 re-read traffic halves (1 GB), MFMA per staged byte doubles.
//     Grid 256 = 1 block/CU (141 KB LDS). 8 waves: wave w -> jq=w&3, i-slab
//     iqb=(w>>2)*32 (two 16-row S-subtiles), PV c-slab cw=w*64.
//   * Keeps R2's V XOR-swizzle (with a filled pipeline, LDS-read is now on the
//     critical path -> T2's regime) + setprio(1) around PV MFMA cluster (T5).
__global__ __launch_bounds__(512, 2) void k23_fused(const bfu* __restrict__ Kb, const bfu* __restrict__ Qb,
                                                    const bfu* __restrict__ Vb,
                                                    const float* __restrict__ x, const float* __restrict__ alpha,
                                                    float* __restrict__ out)
{
    __shared__ bfu   Vs[2][512 * 64];   // 2 x 64 KB, linear DMA dest; rows slot-swizzled
    __shared__ bfu   Ps[TI * 72];       // 9 KB P-tile [i][j], pad 72
    __shared__ float LSum[8][2][16];
    __shared__ float Scale[TI];

    const int t = threadIdx.x;
    const int lane = t & 63, w = t >> 6;
    const int l15 = lane & 15, quad = lane >> 4;
    const int jq  = w & 3;              // S-role: j-subtile
    const int iqb = (w >> 2) * 32;      // S-role: 32-row i-slab (two 16-row subtiles)
    const int cw  = w * 64;             // PV slab: channels cw..cw+63

    // XCD swizzle: 256 blocks, dispatch d -> XCD d&7; XCDs {2b,2b+1} own batch b.
    const int d    = blockIdx.x;        // 0..255
    const int xcd  = d & 7;
    const int slot = d >> 3;            // 0..31
    const int b    = xcd >> 1;
    const int i0   = ((xcd & 1) * 32 + slot) * TI;

    // persistent K fragments (B-side of S-MFMA), two i-subtiles
    const bfu* kp0 = Kb + ((size_t)(b * HW + i0 + iqb + l15)) * C8 + quad * 8;
    const bfu* kp1 = kp0 + (size_t)16 * C8;
    const bf16x8 Kf00 = *(const bf16x8*)kp0;
    const bf16x8 Kf01 = *(const bf16x8*)(kp0 + 32);
    const bf16x8 Kf10 = *(const bf16x8*)kp1;
    const bf16x8 Kf11 = *(const bf16x8*)(kp1 + 32);

    // V staging: thread t fills LDS rows (t>>3)+64p at slot (t&7); global column
    // pre-swizzled so linear LDS receives the swizzled layout (rule #21 / m173).
    const int srow = t >> 3, sslot = t & 7;
    const bfu* gV = Vb + ((size_t)(b * NF + srow)) * HW + ((sslot ^ (srow & 7)) * 8);

    // Q stream base (A-side of S-MFMA): m = j = jb + jq*16 + l15
    const bfu* qbase = Qb + ((size_t)(b * HW + jq * 16 + l15)) * C8 + quad * 8;

    // swizzled PV read slots: row = cw + mt*16 + l15 -> row&7 == l15&7
    const int r7  = l15 & 7;
    const int sl0 = (quad ^ r7) * 8;
    const int sl1 = ((quad + 4) ^ r7) * 8;

    f32x4 acc[4][4];
    #pragma unroll
    for (int mt = 0; mt < 4; mt++)
        #pragma unroll
        for (int nt = 0; nt < 4; nt++) acc[mt][nt] = (f32x4){0.f, 0.f, 0.f, 0.f};
    float rs0 = 0.f, rs1 = 0.f;
    bf16x8 Aq[2][2];                    // Q frag double-buffer [parity][half]

    // prologue: stage chunk 0 into Vs[0], prefetch Q(0).
    // vmem ledger entering iter 0: [Kf x4, stage(0) x8, Qload(0) x2] = 14.
    {
        bfu* lv = &Vs[0][t * 8];
        #pragma unroll
        for (int p = 0; p < 8; p++) gload16(gV + (size_t)(p * 64) * HW, lv + p * 4096);
        Aq[0][0] = *(const bf16x8*)qbase;
        Aq[0][1] = *(const bf16x8*)(qbase + 32);
    }

// one pipelined chunk iteration; pc/pn are compile-time parities (rule #20)
#define K23_ITER(q, pc, pn)                                                                    \
  {                                                                                            \
    const int jn = (((q) + 1) & 63) * 64;                                                      \
    /* stage chunk q+1 into buf pn (8 vmem) + prefetch Q(q+1) (2 vmem) */                      \
    bfu* lv = &Vs[pn][t * 8];                                                                  \
    _Pragma("unroll")                                                                          \
    for (int p = 0; p < 8; p++)                                                                \
        gload16(gV + (size_t)(p * 64) * HW + jn, lv + p * 4096);                               \
    {                                                                                          \
        const bfu* qpn = qbase + (size_t)jn * C8;                                              \
        Aq[pn][0] = *(const bf16x8*)qpn;                                                       \
        Aq[pn][1] = *(const bf16x8*)(qpn + 32);                                                \
    }                                                                                          \
    /* retire everything older than this iter's 10 issues: chunk q's stage+Q (+Kf at q=0) */   \
    asm volatile("s_waitcnt vmcnt(10)" ::: "memory");                                          \
    __builtin_amdgcn_sched_barrier(0);                                                         \
    /* S-step: D[j][i] = Q[j][c].K[i][c] for both i-subtiles */                                \
    {                                                                                          \
        f32x4 s0 = (f32x4){0.f,0.f,0.f,0.f}, s1 = (f32x4){0.f,0.f,0.f,0.f};                    \
        s0 = __builtin_amdgcn_mfma_f32_16x16x32_bf16(Aq[pc][0], Kf00, s0, 0, 0, 0);            \
        s0 = __builtin_amdgcn_mfma_f32_16x16x32_bf16(Aq[pc][1], Kf01, s0, 0, 0, 0);            \
        s1 = __builtin_amdgcn_mfma_f32_16x16x32_bf16(Aq[pc][0], Kf10, s1, 0, 0, 0);            \
        s1 = __builtin_amdgcn_mfma_f32_16x16x32_bf16(Aq[pc][1], Kf11, s1, 0, 0, 0);            \
        float e0 = __expf(s0[0]), e1 = __expf(s0[1]), e2 = __expf(s0[2]), e3 = __expf(s0[3]);  \
        float f0 = __expf(s1[0]), f1 = __expf(s1[1]), f2 = __expf(s1[2]), f3 = __expf(s1[3]);  \
        rs0 += (e0 + e1) + (e2 + e3);                                                          \
        rs1 += (f0 + f1) + (f2 + f3);                                                          \
        uint2 pk0, pk1;                                                                        \
        pk0.x = (unsigned)f2bu(e0) | ((unsigned)f2bu(e1) << 16);                               \
        pk0.y = (unsigned)f2bu(e2) | ((unsigned)f2bu(e3) << 16);                               \
        pk1.x = (unsigned)f2bu(f0) | ((unsigned)f2bu(f1) << 16);                               \
        pk1.y = (unsigned)f2bu(f2) | ((unsigned)f2bu(f3) << 16);                               \
        *(uint2*)(Ps + (iqb + l15)      * 72 + jq * 16 + quad * 4) = pk0;                      \
        *(uint2*)(Ps + (iqb + 16 + l15) * 72 + jq * 16 + quad * 4) = pk1;                      \
    }                                                                                          \
    asm volatile("s_waitcnt lgkmcnt(0)" ::: "memory");                                         \
    __builtin_amdgcn_sched_barrier(0);                                                         \
    __builtin_amdgcn_s_barrier();   /* Vs[pc] staged by all + Ps visible */                    \
    /* PV: D[c][i] += V[c][j].P[i][j] from buf pc */                                           \
    {                                                                                          \
        bf16x8 Pf[4][2];                                                                       \
        _Pragma("unroll")                                                                      \
        for (int nt = 0; nt < 4; nt++) {                                                       \
            Pf[nt][0] = *(const bf16x8*)(Ps + (nt * 16 + l15) * 72 + quad * 8);                \
            Pf[nt][1] = *(const bf16x8*)(Ps + (nt * 16 + l15) * 72 + 32 + quad * 8);           \
        }                                                                                      \
        __builtin_amdgcn_s_setprio(1);                                                         \
        _Pragma("unroll")                                                                      \
        for (int mt = 0; mt < 4; mt++) {                                                       \
            const bfu* vrow = &Vs[pc][(cw + mt * 16 + l15) * 64];                              \
            bf16x8 V0 = *(const bf16x8*)(vrow + sl0);                                          \
            bf16x8 V1 = *(const bf16x8*)(vrow + sl1);                                          \
            _Pragma("unroll")                                                                  \
            for (int nt = 0; nt < 4; nt++) {                                                   \
                acc[mt][nt] = __builtin_amdgcn_mfma_f32_16x16x32_bf16(V0, Pf[nt][0], acc[mt][nt], 0, 0, 0); \
                acc[mt][nt] = __builtin_amdgcn_mfma_f32_16x16x32_bf16(V1, Pf[nt][1], acc[mt][nt], 0, 0, 0); \
            }                                                                                  \
        }                                                                                      \
        __builtin_amdgcn_s_setprio(0);                                                         \
    }                                                                                          \
    __builtin_amdgcn_sched_barrier(0);                                                         \
    __builtin_amdgcn_s_barrier();   /* all PV reads of Vs[pc]/Ps done -> restage/rewrite ok */ \
  }

    for (int qq = 0; qq < 32; qq++) {
        K23_ITER(2 * qq,     0, 1)
        K23_ITER(2 * qq + 1, 1, 0)
    }
#undef K23_ITER

    // row-sum reduction: rs0/rs1 cover i = i0 + iqb + {0,16} + l15, j in lane's (jq,quad,r) set
    float sred0 = rs0, sred1 = rs1;
    sred0 += __shfl_xor(sred0, 16, 64);
    sred0 += __shfl_xor(sred0, 32, 64);
    sred1 += __shfl_xor(sred1, 16, 64);
    sred1 += __shfl_xor(sred1, 32, 64);
    if (quad == 0) { LSum[w][0][l15] = sred0; LSum[w][1][l15] = sred1; }
    __syncthreads();
    if (t < TI) {
        int u = t >> 5, s = (t >> 4) & 1, il = t & 15;
        float L = (LSum[u * 4 + 0][s][il] + LSum[u * 4 + 1][s][il])
                + (LSum[u * 4 + 2][s][il] + LSum[u * 4 + 3][s][il]);
        Scale[t] = alpha[0] / L;
    }
    __syncthreads();

    #pragma unroll
    for (int nt = 0; nt < 4; nt++) {
        float sc = Scale[nt * 16 + l15];
        int i = i0 + nt * 16 + l15;
        #pragma unroll
        for (int mt = 0; mt < 4; mt++)
            #pragma unroll
            for (int r = 0; r < 4; r++) {
                int c = cw + mt * 16 + quad * 4 + r;
                size_t idx = ((size_t)(b * NF + c)) * HW + i;
                out[idx] = x[idx] + sc * acc[mt][nt][r];
            }
    }
}

extern "C" void kernel_launch(void* const* d_in, const int* in_sizes, int n_in,
                              void* d_out, int out_size, void* d_ws, size_t ws_size,
                              hipStream_t stream)
{
    const float* x     = (const float*)d_in[0];
    const float* Wq    = (const float*)d_in[1];
    const float* bq    = (const float*)d_in[2];
    const float* Wk    = (const float*)d_in[3];
    const float* bk    = (const float*)d_in[4];
    const float* Wv    = (const float*)d_in[5];
    const float* bv    = (const float*)d_in[6];
    const float* alpha = (const float*)d_in[7];
    float* out = (float*)d_out;

    char* ws = (char*)d_ws;
    bfu*   xt   = (bfu*)(ws);                                  // [0,16) MB : [b][n][c] bf16
    bfu*   Wb   = (bfu*)(ws + (16u << 20));                    // [16,~16.6) MB: [640][512] bf16
    float* bcat = (float*)(ws + (17u << 20));                  // 2.5 KB at 17 MB
    bfu*   Qb   = (bfu*)(ws + (18u << 20));                    // [18,20) MB : [b][n][64]
    bfu*   Kb   = (bfu*)(ws + (20u << 20));                    // [20,22) MB : [b][n][64]
    bfu*   Vb   = (bfu*)(ws + (22u << 20));                    // [22,38) MB : [b][c][n]  (16 MB)

    k0_xt<<<dim3(HW / 64, NF / 64, BS), 256, 0, stream>>>(x, xt);
    k0_w<<<dim3(640), 256, 0, stream>>>(Wq, bq, Wk, bk, Wv, bv, Wb, bcat);
    k1_proj<<<dim3(5, HW / 128, BS), 256, 0, stream>>>(Wb, bcat, xt, Qb, Kb, Vb);
    k23_fused<<<dim3(HW / TI * BS), 512, 0, stream>>>(Kb, Qb, Vb, x, alpha, out);
}

// Round 4
// 240.554 us; speedup vs baseline: 1.7508x; 1.1010x over previous
//
#include <hip/hip_runtime.h>

#define BS 4
#define NF 512
#define HW 4096
#define C8 64
#define TI 64                       // i-rows per fused block

typedef unsigned short bfu;                                    // raw bf16 bits
typedef __attribute__((ext_vector_type(8))) short bf16x8;      // MFMA A/B frag (4 VGPRs)
typedef __attribute__((ext_vector_type(4))) float f32x4;       // MFMA C/D frag

static __device__ __forceinline__ bfu f2bu(float v) {
    union { unsigned int u; float f; } c; c.f = v;
    unsigned int u = c.u;
    u = u + 0x7FFFu + ((u >> 16) & 1u);   // round-to-nearest-even
    return (bfu)(u >> 16);
}

// pack 2 f32 -> 2 bf16 (RNE), one instruction (T12 primitive; no builtin on gfx950)
static __device__ __forceinline__ unsigned int cvt_pk_bf16(float lo, float hi) {
    unsigned int r;
    asm("v_cvt_pk_bf16_f32 %0, %1, %2" : "=v"(r) : "v"(lo), "v"(hi));
    return r;
}

// async global->LDS, 16 B per lane (global_load_lds_dwordx4)
static __device__ __forceinline__ void gload16(const void* g, void* l) {
    __builtin_amdgcn_global_load_lds(
        (const __attribute__((address_space(1))) unsigned int*)g,
        (__attribute__((address_space(3))) unsigned int*)l,
        16, 0, 0);
}

// ---------------- k0: x fp32 [b][c][n] -> xt bf16 [b][n][c] ----------------
// R4: column-group XOR swizzle on T fixes the 8-way read conflict
// (read stride 8 rows x 68 words = 544 = 0 mod 32 -> 8 lanes/bank).
__global__ __launch_bounds__(256) void k0_xt(const float* __restrict__ x, bfu* __restrict__ xt)
{
    __shared__ float T[64][68];
    const int t  = threadIdx.x;
    const int n0 = blockIdx.x * 64;
    const int c0 = blockIdx.y * 64;
    const int b  = blockIdx.z;

    #pragma unroll
    for (int u = 0; u < 4; u++) {
        int f4 = u * 256 + t;
        int cc = f4 >> 4;
        int n4 = (f4 & 15) << 2;
        float4 v = *(const float4*)(x + ((size_t)(b * NF + c0 + cc)) * HW + n0 + n4);
        *(float4*)&T[cc][n4 ^ (((cc >> 3) & 3) << 2)] = v;     // group-XOR by row bits 3..4
    }
    __syncthreads();
    #pragma unroll
    for (int u = 0; u < 2; u++) {
        int e8 = u * 256 + t;
        int nn = e8 >> 3;
        int c8 = (e8 & 7) << 3;
        union { int4 i4; bfu h[8]; } pk;
        #pragma unroll
        for (int q = 0; q < 8; q++)
            pk.h[q] = f2bu(T[c8 + q][nn ^ ((((c8 + q) >> 3) & 3) << 2)]);
        *(int4*)(xt + ((size_t)(b * HW + n0 + nn)) * NF + c0 + c8) = pk.i4;
    }
}

// ---------------- k0b: Wq|Wk|Wv -> Wb bf16 [640][512]; biases -> bcat[640] ----------------
__global__ __launch_bounds__(256) void k0_w(const float* __restrict__ Wq, const float* __restrict__ bq,
                                            const float* __restrict__ Wk, const float* __restrict__ bk,
                                            const float* __restrict__ Wv, const float* __restrict__ bv,
                                            bfu* __restrict__ Wb, float* __restrict__ bcat)
{
    const int o = blockIdx.x;                   // 0..639
    const int t = threadIdx.x;
    const float* src; float bias;
    if (o < 64)       { src = Wq + (size_t)o * NF;          bias = bq[o]; }
    else if (o < 128) { src = Wk + (size_t)(o - 64) * NF;   bias = bk[o - 64]; }
    else              { src = Wv + (size_t)(o - 128) * NF;  bias = bv[o - 128]; }
    float2 v = *(const float2*)(src + t * 2);
    Wb[(size_t)o * NF + t * 2 + 0] = f2bu(v.x);
    Wb[(size_t)o * NF + t * 2 + 1] = f2bu(v.y);
    if (t == 0) bcat[o] = bias;
}

// ---------------- k1: Out[o][n] = Wb(640x512) . xt[b]^T, scatter into Qb/Kb/Vb ----------------
// R4: counted-vmcnt double-buffered pipeline (no drain barriers), XOR-swizzled
// A/B tiles (slot ^ row&7, pre-swizzled global source + matching read slot),
// int2-packed Q/K epilogue stores. Same fixes that took k23 from 170->142.
__global__ __launch_bounds__(256) void k1_proj(const bfu* __restrict__ Wb, const float* __restrict__ bcat,
                                               const bfu* __restrict__ xt,
                                               bfu* __restrict__ Qb, bfu* __restrict__ Kb, bfu* __restrict__ Vb)
{
    __shared__ bfu As[2][128 * 64];
    __shared__ bfu Bs[2][128 * 64];
    const int t  = threadIdx.x;
    const int o0 = blockIdx.x * 128;
    const int n0 = blockIdx.y * 128;
    const int b  = blockIdx.z;
    const int lane = t & 63, wv = t >> 6;
    const int wm = wv & 1, wn = wv >> 1;
    const int l15 = lane & 15, quad = lane >> 4;
    const int r7  = l15 & 7;
    const int sl0 = (quad ^ r7) * 8;            // swizzled slot, kk=0
    const int sl1 = ((quad + 4) ^ r7) * 8;      // swizzled slot, kk=32

    const int srow = t >> 3;                    // 0..31
    const int scolz = ((t & 7) ^ (srow & 7)) * 8;   // pre-swizzled source column

    const bfu* gA = Wb + ((size_t)(o0 + srow)) * NF + scolz;
    const bfu* gB = xt + ((size_t)(b * HW + n0 + srow)) * NF + scolz;

    f32x4 acc[4][4];
    #pragma unroll
    for (int m = 0; m < 4; m++)
        #pragma unroll
        for (int n = 0; n < 4; n++) acc[m][n] = (f32x4){0.f, 0.f, 0.f, 0.f};

#define K1_STAGE(buf, c0)                                                       \
    _Pragma("unroll")                                                           \
    for (int p = 0; p < 4; p++) {                                               \
        gload16(gA + (size_t)(p * 32) * NF + (c0), &As[buf][t * 8 + p * 2048]); \
        gload16(gB + (size_t)(p * 32) * NF + (c0), &Bs[buf][t * 8 + p * 2048]); \
    }

#define K1_COMPUTE(pc)                                                                      \
    {                                                                                       \
        bf16x8 Af0[4], Af1[4], Bf0[4], Bf1[4];                                              \
        _Pragma("unroll")                                                                   \
        for (int m = 0; m < 4; m++) {                                                       \
            const bfu* ar = &As[pc][(wm * 64 + m * 16 + l15) * 64];                         \
            Af0[m] = *(const bf16x8*)(ar + sl0);                                            \
            Af1[m] = *(const bf16x8*)(ar + sl1);                                            \
        }                                                                                   \
        _Pragma("unroll")                                                                   \
        for (int n = 0; n < 4; n++) {                                                       \
            const bfu* br = &Bs[pc][(wn * 64 + n * 16 + l15) * 64];                         \
            Bf0[n] = *(const bf16x8*)(br + sl0);                                            \
            Bf1[n] = *(const bf16x8*)(br + sl1);                                            \
        }                                                                                   \
        __builtin_amdgcn_s_setprio(1);                                                      \
        _Pragma("unroll")                                                                   \
        for (int m = 0; m < 4; m++)                                                         \
            _Pragma("unroll")                                                               \
            for (int n = 0; n < 4; n++) {                                                   \
                acc[m][n] = __builtin_amdgcn_mfma_f32_16x16x32_bf16(Af0[m], Bf0[n], acc[m][n], 0, 0, 0); \
                acc[m][n] = __builtin_amdgcn_mfma_f32_16x16x32_bf16(Af1[m], Bf1[n], acc[m][n], 0, 0, 0); \
            }                                                                               \
        __builtin_amdgcn_s_setprio(0);                                                      \
    }

    K1_STAGE(0, 0)                              // prologue: 8 vmem outstanding
    for (int it = 0; it < 7; it++) {
        const int pc = it & 1;
        K1_STAGE(pc ^ 1, (it + 1) * 64)         // +8 vmem -> 16
        asm volatile("s_waitcnt vmcnt(8)" ::: "memory");   // retire stage(it)
        __builtin_amdgcn_sched_barrier(0);
        __builtin_amdgcn_s_barrier();           // buf[pc] ready for all waves
        K1_COMPUTE(pc)
        __builtin_amdgcn_sched_barrier(0);
        __builtin_amdgcn_s_barrier();           // reads done -> restage ok
    }
    asm volatile("s_waitcnt vmcnt(0)" ::: "memory");
    __builtin_amdgcn_sched_barrier(0);
    __builtin_amdgcn_s_barrier();
    K1_COMPUTE(1)                               // c0 = 7 lives in buf 1
#undef K1_STAGE
#undef K1_COMPUTE

    if (o0 == 0) {
        // Q/K channels: pack 4 consecutive go (quad*4 + r) into one int2 store
        #pragma unroll
        for (int mt = 0; mt < 4; mt++)
            #pragma unroll
            for (int nt = 0; nt < 4; nt++) {
                int goq = wm * 64 + mt * 16 + quad * 4;              // 0..124
                int n   = n0 + wn * 64 + nt * 16 + l15;
                float v0 = acc[mt][nt][0] + bcat[goq + 0];
                float v1 = acc[mt][nt][1] + bcat[goq + 1];
                float v2 = acc[mt][nt][2] + bcat[goq + 2];
                float v3 = acc[mt][nt][3] + bcat[goq + 3];
                int2 pk;
                pk.x = (int)cvt_pk_bf16(v0, v1);
                pk.y = (int)cvt_pk_bf16(v2, v3);
                if (wm == 0) *(int2*)(Qb + ((size_t)(b * HW + n)) * C8 + goq)      = pk;
                else         *(int2*)(Kb + ((size_t)(b * HW + n)) * C8 + goq - 64) = pk;
            }
    } else {
        #pragma unroll
        for (int mt = 0; mt < 4; mt++)
            #pragma unroll
            for (int nt = 0; nt < 4; nt++)
                #pragma unroll
                for (int r = 0; r < 4; r++) {
                    int go = o0 + wm * 64 + mt * 16 + quad * 4 + r;  // 128..639
                    int n  = n0 + wn * 64 + nt * 16 + l15;
                    float val = acc[mt][nt][r] + bcat[go];
                    Vb[((size_t)(b * NF + (go - 128))) * HW + n] = f2bu(val);
                }
    }
}

// ---------------- k23: fused scores + softmax-numerator + PV + residual ----------------
// R4: c-split for 2 blocks/CU. R3's 141 KB LDS forced 1 block/CU (2 waves/SIMD)
// -> barriers synced the whole CU with nothing to hide behind (5328 cy/chunk vs
// ~1550 cy MFMA floor). Split the PV c-dimension across 2 blocks (cblk): each
// stages half of V (32 KB/chunk, double-buffered), duplicates only the small
// S-step + row-sum. LDS ~76 KB -> 2 independent blocks/CU, 16 waves/CU: the
// co-resident block's MFMAs cover barrier skew and LDS latency.
// Grid 512, XCD-pinned: XCD (2b+cblk) re-reads one 2 MB V-half (fits 4 MB L2).
// Keeps: counted vmcnt(6) (4 stage + 2 Q per iter), V slot^row&7 both-sides
// swizzle, setprio around PV, cvt_pk_bf16 for the P pack (saves ~30 VALU/chunk).
__global__ __launch_bounds__(512, 4) void k23_fused(const bfu* __restrict__ Kb, const bfu* __restrict__ Qb,
                                                    const bfu* __restrict__ Vb,
                                                    const float* __restrict__ x, const float* __restrict__ alpha,
                                                    float* __restrict__ out)
{
    __shared__ bfu   Vs[2][256 * 64];   // 2 x 32 KB, linear DMA dest; rows slot-swizzled
    __shared__ bfu   Ps[TI * 72];       // 9 KB P-tile [i][j], pad 72
    __shared__ float LSum[8][2][16];
    __shared__ float Scale[TI];

    const int t = threadIdx.x;
    const int lane = t & 63, w = t >> 6;
    const int l15 = lane & 15, quad = lane >> 4;
    const int jq  = w & 3;              // S-role: j-subtile
    const int iqb = (w >> 2) * 32;      // S-role: 32-row i-slab (two 16-row subtiles)

    // XCD pinning: d&7 -> XCD; b = xcd>>1, cblk = xcd&1; i0 from d>>3.
    const int d    = blockIdx.x;        // 0..511
    const int xcd  = d & 7;
    const int b    = xcd >> 1;
    const int cblk = xcd & 1;           // which 256-channel half of V/out
    const int i0   = (d >> 3) * TI;     // 0..4032

    // persistent K fragments (B-side of S-MFMA), two i-subtiles
    const bfu* kp0 = Kb + ((size_t)(b * HW + i0 + iqb + l15)) * C8 + quad * 8;
    const bfu* kp1 = kp0 + (size_t)16 * C8;
    const bf16x8 Kf00 = *(const bf16x8*)kp0;
    const bf16x8 Kf01 = *(const bf16x8*)(kp0 + 32);
    const bf16x8 Kf10 = *(const bf16x8*)kp1;
    const bf16x8 Kf11 = *(const bf16x8*)(kp1 + 32);

    // V staging: thread t fills rows (t>>3)+64p (0..255 within the half) at
    // slot (t&7); global column pre-swizzled (slot ^ row&7) so the linear DMA
    // dest receives the swizzled layout (rule #21 / m173).
    const int srow = t >> 3, sslot = t & 7;
    const bfu* gV = Vb + ((size_t)(b * NF + cblk * 256 + srow)) * HW + ((sslot ^ (srow & 7)) * 8);

    // Q stream base (A-side of S-MFMA): m = j = jb + jq*16 + l15
    const bfu* qbase = Qb + ((size_t)(b * HW + jq * 16 + l15)) * C8 + quad * 8;

    // swizzled PV read slots: row = w*32 + mt*16 + l15 -> row&7 == l15&7
    const int r7  = l15 & 7;
    const int sl0 = (quad ^ r7) * 8;
    const int sl1 = ((quad + 4) ^ r7) * 8;

    f32x4 acc[2][4];
    #pragma unroll
    for (int mt = 0; mt < 2; mt++)
        #pragma unroll
        for (int nt = 0; nt < 4; nt++) acc[mt][nt] = (f32x4){0.f, 0.f, 0.f, 0.f};
    float rs0 = 0.f, rs1 = 0.f;
    bf16x8 Aq[2][2];                    // Q frag double-buffer [parity][half]

    // prologue: stage chunk 0 into Vs[0], prefetch Q(0).
    // vmem ledger entering iter 0: [Kf x4, stage(0) x4, Qload(0) x2] = 10.
    {
        #pragma unroll
        for (int p = 0; p < 4; p++)
            gload16(gV + (size_t)(p * 64) * HW, &Vs[0][t * 8 + p * 4096]);
        Aq[0][0] = *(const bf16x8*)qbase;
        Aq[0][1] = *(const bf16x8*)(qbase + 32);
    }

// one pipelined chunk iteration; pc/pn are compile-time parities (rule #20)
#define K23_ITER(q, pc, pn)                                                                    \
  {                                                                                            \
    const int jn = (((q) + 1) & 63) * 64;                                                      \
    /* stage chunk q+1 into buf pn (4 vmem) + prefetch Q(q+1) (2 vmem) */                      \
    _Pragma("unroll")                                                                          \
    for (int p = 0; p < 4; p++)                                                                \
        gload16(gV + (size_t)(p * 64) * HW + jn, &Vs[pn][t * 8 + p * 4096]);                   \
    {                                                                                          \
        const bfu* qpn = qbase + (size_t)jn * C8;                                              \
        Aq[pn][0] = *(const bf16x8*)qpn;                                                       \
        Aq[pn][1] = *(const bf16x8*)(qpn + 32);                                                \
    }                                                                                          \
    /* retire everything older than this iter's 6 issues (chunk q's stage+Q, +Kf at q=0) */    \
    asm volatile("s_waitcnt vmcnt(6)" ::: "memory");                                           \
    __builtin_amdgcn_sched_barrier(0);                                                         \
    /* S-step: D[j][i] = Q[j][c].K[i][c] for both i-subtiles */                                \
    {                                                                                          \
        f32x4 s0 = (f32x4){0.f,0.f,0.f,0.f}, s1 = (f32x4){0.f,0.f,0.f,0.f};                    \
        s0 = __builtin_amdgcn_mfma_f32_16x16x32_bf16(Aq[pc][0], Kf00, s0, 0, 0, 0);            \
        s0 = __builtin_amdgcn_mfma_f32_16x16x32_bf16(Aq[pc][1], Kf01, s0, 0, 0, 0);            \
        s1 = __builtin_amdgcn_mfma_f32_16x16x32_bf16(Aq[pc][0], Kf10, s1, 0, 0, 0);            \
        s1 = __builtin_amdgcn_mfma_f32_16x16x32_bf16(Aq[pc][1], Kf11, s1, 0, 0, 0);            \
        float e0 = __expf(s0[0]), e1 = __expf(s0[1]), e2 = __expf(s0[2]), e3 = __expf(s0[3]);  \
        float f0 = __expf(s1[0]), f1 = __expf(s1[1]), f2 = __expf(s1[2]), f3 = __expf(s1[3]);  \
        rs0 += (e0 + e1) + (e2 + e3);                                                          \
        rs1 += (f0 + f1) + (f2 + f3);                                                          \
        uint2 pk0, pk1;                                                                        \
        pk0.x = cvt_pk_bf16(e0, e1);  pk0.y = cvt_pk_bf16(e2, e3);                             \
        pk1.x = cvt_pk_bf16(f0, f1);  pk1.y = cvt_pk_bf16(f2, f3);                             \
        *(uint2*)(Ps + (iqb + l15)      * 72 + jq * 16 + quad * 4) = pk0;                      \
        *(uint2*)(Ps + (iqb + 16 + l15) * 72 + jq * 16 + quad * 4) = pk1;                      \
    }                                                                                          \
    asm volatile("s_waitcnt lgkmcnt(0)" ::: "memory");                                         \
    __builtin_amdgcn_sched_barrier(0);                                                         \
    __builtin_amdgcn_s_barrier();   /* Vs[pc] staged by all + Ps visible */                    \
    /* PV: D[c][i] += V[c][j].P[i][j] from buf pc */                                           \
    {                                                                                          \
        bf16x8 Pf[4][2];                                                                       \
        _Pragma("unroll")                                                                      \
        for (int nt = 0; nt < 4; nt++) {                                                       \
            Pf[nt][0] = *(const bf16x8*)(Ps + (nt * 16 + l15) * 72 + quad * 8);                \
            Pf[nt][1] = *(const bf16x8*)(Ps + (nt * 16 + l15) * 72 + 32 + quad * 8);           \
        }                                                                                      \
        __builtin_amdgcn_s_setprio(1);                                                         \
        _Pragma("unroll")                                                                      \
        for (int mt = 0; mt < 2; mt++) {                                                       \
            const bfu* vrow = &Vs[pc][(w * 32 + mt * 16 + l15) * 64];                          \
            bf16x8 V0 = *(const bf16x8*)(vrow + sl0);                                          \
            bf16x8 V1 = *(const bf16x8*)(vrow + sl1);                                          \
            _Pragma("unroll")                                                                  \
            for (int nt = 0; nt < 4; nt++) {                                                   \
                acc[mt][nt] = __builtin_amdgcn_mfma_f32_16x16x32_bf16(V0, Pf[nt][0], acc[mt][nt], 0, 0, 0); \
                acc[mt][nt] = __builtin_amdgcn_mfma_f32_16x16x32_bf16(V1, Pf[nt][1], acc[mt][nt], 0, 0, 0); \
            }                                                                                  \
        }                                                                                      \
        __builtin_amdgcn_s_setprio(0);                                                         \
    }                                                                                          \
    __builtin_amdgcn_sched_barrier(0);                                                         \
    __builtin_amdgcn_s_barrier();   /* all PV reads of Vs[pc]/Ps done -> restage/rewrite ok */ \
  }

    for (int qq = 0; qq < 32; qq++) {
        K23_ITER(2 * qq,     0, 1)
        K23_ITER(2 * qq + 1, 1, 0)
    }
#undef K23_ITER

    // row-sum reduction: rs0/rs1 cover i = i0 + iqb + {0,16} + l15, j in lane's (jq,quad,r) set
    float sred0 = rs0, sred1 = rs1;
    sred0 += __shfl_xor(sred0, 16, 64);
    sred0 += __shfl_xor(sred0, 32, 64);
    sred1 += __shfl_xor(sred1, 16, 64);
    sred1 += __shfl_xor(sred1, 32, 64);
    if (quad == 0) { LSum[w][0][l15] = sred0; LSum[w][1][l15] = sred1; }
    __syncthreads();
    if (t < TI) {
        int u = t >> 5, s = (t >> 4) & 1, il = t & 15;
        float L = (LSum[u * 4 + 0][s][il] + LSum[u * 4 + 1][s][il])
                + (LSum[u * 4 + 2][s][il] + LSum[u * 4 + 3][s][il]);
        Scale[t] = alpha[0] / L;
    }
    __syncthreads();

    #pragma unroll
    for (int nt = 0; nt < 4; nt++) {
        float sc = Scale[nt * 16 + l15];
        int i = i0 + nt * 16 + l15;
        #pragma unroll
        for (int mt = 0; mt < 2; mt++)
            #pragma unroll
            for (int r = 0; r < 4; r++) {
                int c = cblk * 256 + w * 32 + mt * 16 + quad * 4 + r;
                size_t idx = ((size_t)(b * NF + c)) * HW + i;
                out[idx] = x[idx] + sc * acc[mt][nt][r];
            }
    }
}

extern "C" void kernel_launch(void* const* d_in, const int* in_sizes, int n_in,
                              void* d_out, int out_size, void* d_ws, size_t ws_size,
                              hipStream_t stream)
{
    const float* x     = (const float*)d_in[0];
    const float* Wq    = (const float*)d_in[1];
    const float* bq    = (const float*)d_in[2];
    const float* Wk    = (const float*)d_in[3];
    const float* bk    = (const float*)d_in[4];
    const float* Wv    = (const float*)d_in[5];
    const float* bv    = (const float*)d_in[6];
    const float* alpha = (const float*)d_in[7];
    float* out = (float*)d_out;

    char* ws = (char*)d_ws;
    bfu*   xt   = (bfu*)(ws);                                  // [0,16) MB : [b][n][c] bf16
    bfu*   Wb   = (bfu*)(ws + (16u << 20));                    // [16,~16.6) MB: [640][512] bf16
    float* bcat = (float*)(ws + (17u << 20));                  // 2.5 KB at 17 MB
    bfu*   Qb   = (bfu*)(ws + (18u << 20));                    // [18,20) MB : [b][n][64]
    bfu*   Kb   = (bfu*)(ws + (20u << 20));                    // [20,22) MB : [b][n][64]
    bfu*   Vb   = (bfu*)(ws + (22u << 20));                    // [22,38) MB : [b][c][n]  (16 MB)

    k0_xt<<<dim3(HW / 64, NF / 64, BS), 256, 0, stream>>>(x, xt);
    k0_w<<<dim3(640), 256, 0, stream>>>(Wq, bq, Wk, bk, Wv, bv, Wb, bcat);
    k1_proj<<<dim3(5, HW / 128, BS), 256, 0, stream>>>(Wb, bcat, xt, Qb, Kb, Vb);
    k23_fused<<<dim3(HW / TI * BS * 2), 512, 0, stream>>>(Kb, Qb, Vb, x, alpha, out);
}